// Round 7
// baseline (328.304 us; speedup 1.0000x reference)
//
#include <hip/hip_runtime.h>

#define N_NODES 100000
#define N_EDGES 1600000
#define D_IN 128
#define D_HID 64
#define SLOTS 64   // max in-degree guard; Poisson(16) -> P(deg>=64) ~ 1e-20

typedef __attribute__((ext_vector_type(8))) short bf16x8;
typedef __attribute__((ext_vector_type(4))) float f32x4;

__device__ __forceinline__ unsigned short f2b(float f) {
    union { float f; unsigned u; } c; c.f = f;
    unsigned r = (c.u + 0x7FFFu + ((c.u >> 16) & 1u)) >> 16;   // RNE
    return (unsigned short)r;
}

// ================= degree counters =================
__global__ void k_zero(int* __restrict__ cnt, int n) {
    int i = blockIdx.x * blockDim.x + threadIdx.x;
    if (i < n) cnt[i] = 0;
}

// ================= direct slot build: slots[dst*64 + c] = src =================
__global__ void k_slot(const int* __restrict__ src, const int* __restrict__ dst,
                       int* __restrict__ cnt, int* __restrict__ slots, int E) {
    int e = blockIdx.x * blockDim.x + threadIdx.x;
    if (e < E) {
        int d = dst[e];
        int c = atomicAdd(&cnt[d], 1);
        if (c < SLOTS) slots[(size_t)d * SLOTS + c] = src[e];
    }
}

__global__ void k_dis(const int* __restrict__ cnt, float* __restrict__ dis, int n) {
    int i = blockIdx.x * blockDim.x + threadIdx.x;
    if (i < n) dis[i] = rsqrtf((float)cnt[i] + 1.0f);
}

// ================= layer 1 GEMM via bf16 MFMA: h1[node][f] fp32 =================
#define LS 136
__global__ __launch_bounds__(256) void k_gemm1(const float* __restrict__ x,
                                               const float* __restrict__ W1,
                                               float* __restrict__ h1, int n) {
    __shared__ unsigned short xs[64 * LS];
    __shared__ unsigned short ws[64 * LS];
    int tid = threadIdx.x;
    int node0 = blockIdx.x * 64;

    for (int i = 0; i < 32; ++i) {
        int e = tid + i * 256;
        int k = e >> 6, f = e & 63;
        ws[f * LS + k] = f2b(W1[e]);
    }
    for (int i = 0; i < 8; ++i) {
        int e4 = tid + i * 256;
        int node = e4 >> 5;
        int k = (e4 & 31) * 4;
        float4 v = make_float4(0.f, 0.f, 0.f, 0.f);
        if (node0 + node < n)
            v = ((const float4*)x)[((size_t)(node0 + node) * D_IN + k) >> 2];
        unsigned short* p = &xs[node * LS + k];
        p[0] = f2b(v.x); p[1] = f2b(v.y); p[2] = f2b(v.z); p[3] = f2b(v.w);
    }
    __syncthreads();

    int wv = tid >> 6;
    int lane = tid & 63;
    int m16 = lane & 15;
    int q = lane >> 4;

    bf16x8 afrag[4];
#pragma unroll
    for (int ks = 0; ks < 4; ++ks)
        afrag[ks] = *(const bf16x8*)&xs[(wv * 16 + m16) * LS + ks * 32 + q * 8];

    f32x4 acc[4];
#pragma unroll
    for (int ft = 0; ft < 4; ++ft) acc[ft] = (f32x4){0.f, 0.f, 0.f, 0.f};

#pragma unroll
    for (int ft = 0; ft < 4; ++ft)
#pragma unroll
        for (int ks = 0; ks < 4; ++ks) {
            bf16x8 bfrag = *(const bf16x8*)&ws[(ft * 16 + m16) * LS + ks * 32 + q * 8];
            acc[ft] = __builtin_amdgcn_mfma_f32_16x16x32_bf16(afrag[ks], bfrag, acc[ft], 0, 0, 0);
        }

#pragma unroll
    for (int ft = 0; ft < 4; ++ft)
#pragma unroll
        for (int r = 0; r < 4; ++r) {
            int node = node0 + wv * 16 + q * 4 + r;
            if (node < n) h1[(size_t)node * D_HID + ft * 16 + m16] = acc[ft][r];
        }
}

// ================= fused agg1 + bias + ReLU + dot(W2) -> zd = z*dis =================
// One wave per dst node. Lane = (g = edge slot mod 4, m4 = feature quad).
// No shuffles in the loop: 16 lanes of a g-group self-load the same slot (broadcast),
// gather dis[s], one float4 quarter-row of h1, 4 fmas.
__global__ __launch_bounds__(256) void k_gather1(const int* __restrict__ slots,
                                                 const int* __restrict__ cnt,
                                                 const float* __restrict__ dis,
                                                 const float4* __restrict__ h4,
                                                 const float* __restrict__ b1,
                                                 const float* __restrict__ W2,
                                                 float* __restrict__ zd, int n) {
    int i = blockIdx.x * 4 + (threadIdx.x >> 6);
    if (i >= n) return;
    int lane = threadIdx.x & 63;
    int g = lane >> 4;        // edge sub-slot
    int m4 = lane & 15;       // feature quad (feats 4*m4 .. 4*m4+3)
    float dd = dis[i];
    int ci = min(cnt[i], SLOTS);

    float4 a = make_float4(0.f, 0.f, 0.f, 0.f);
    if (g == 0) {             // self-loop
        float4 u = h4[(size_t)i * 16 + m4];
        float w = dd * dd;
        a.x = w * u.x; a.y = w * u.y; a.z = w * u.z; a.w = w * u.w;
    }
    const int* row = slots + (size_t)i * SLOTS;
    for (int j = g; j < ci; j += 4) {
        int s = row[j];                       // 16 lanes same addr -> broadcast
        float w = dis[s] * dd;
        float4 u = h4[(size_t)s * 16 + m4];
        a.x = fmaf(w, u.x, a.x); a.y = fmaf(w, u.y, a.y);
        a.z = fmaf(w, u.z, a.z); a.w = fmaf(w, u.w, a.w);
    }
    // reduce across the 4 g-groups (lane bits 4,5)
#pragma unroll
    for (int off = 16; off < 64; off <<= 1) {
        a.x += __shfl_xor(a.x, off); a.y += __shfl_xor(a.y, off);
        a.z += __shfl_xor(a.z, off); a.w += __shfl_xor(a.w, off);
    }
    float4 bb = ((const float4*)b1)[m4];
    float4 ww = ((const float4*)W2)[m4];
    float v = fmaxf(a.x + bb.x, 0.f) * ww.x + fmaxf(a.y + bb.y, 0.f) * ww.y
            + fmaxf(a.z + bb.z, 0.f) * ww.z + fmaxf(a.w + bb.w, 0.f) * ww.w;
#pragma unroll
    for (int off = 1; off < 16; off <<= 1) v += __shfl_xor(v, off);
    if (lane == 0) zd[i] = v * dd;
}

// ================= agg2 (single masked parallel gather) + fused padded output =====
__global__ __launch_bounds__(256) void k_gather2(const int* __restrict__ slots,
                                                 const int* __restrict__ cnt,
                                                 const float* __restrict__ dis,
                                                 const float* __restrict__ zd,
                                                 const float* __restrict__ b2,
                                                 float* __restrict__ out, int n) {
    int i = blockIdx.x * 4 + (threadIdx.x >> 6);
    if (i >= n) return;
    int lane = threadIdx.x & 63;
    int ci = min(cnt[i], SLOTS);
    float acc = 0.f;
    if (lane < ci) acc = zd[slots[(size_t)i * SLOTS + lane]];
#pragma unroll
    for (int off = 32; off > 0; off >>= 1) acc += __shfl_xor(acc, off);
    float y = (acc + zd[i]) * dis[i] + b2[0];
    float2 v = (lane == 0) ? make_float2(y, 0.f) : make_float2(0.f, 0.f);
    ((float2*)out)[(size_t)i * 64 + lane] = v;
}

extern "C" void kernel_launch(void* const* d_in, const int* in_sizes, int n_in,
                              void* d_out, int out_size, void* d_ws, size_t ws_size,
                              hipStream_t stream) {
    const float* x  = (const float*)d_in[0];
    const int*   ei = (const int*)d_in[1];   // [2, E] int32
    const float* W1 = (const float*)d_in[2];
    const float* b1 = (const float*)d_in[3];
    const float* W2 = (const float*)d_in[4];
    const float* b2 = (const float*)d_in[5];
    float* out = (float*)d_out;

    const int n = N_NODES;
    const int E = N_EDGES;
    const int* src = ei;
    const int* dst = ei + E;

    // ws: cnt int[n] | slots int[n*64] (25.6MB) | dis f[n] | h1 f[n*64] (25.6MB) | zd f[n]
    int* cnt    = (int*)d_ws;
    int* slots  = cnt + n;
    float* dis  = (float*)(slots + (size_t)n * SLOTS);
    float* h1   = dis + n;
    float* zd   = h1 + (size_t)n * D_HID;

    k_zero<<<(n + 255) / 256, 256, 0, stream>>>(cnt, n);
    k_slot<<<(E + 255) / 256, 256, 0, stream>>>(src, dst, cnt, slots, E);
    k_dis<<<(n + 255) / 256, 256, 0, stream>>>(cnt, dis, n);

    k_gemm1<<<(n + 63) / 64, 256, 0, stream>>>(x, W1, h1, n);

    k_gather1<<<(n + 3) / 4, 256, 0, stream>>>(slots, cnt, dis, (const float4*)h1,
                                               b1, W2, zd, n);
    k_gather2<<<(n + 3) / 4, 256, 0, stream>>>(slots, cnt, dis, zd, b2, out, n);
}

// Round 8
// 238.123 us; speedup vs baseline: 1.3787x; 1.3787x over previous
//
#include <hip/hip_runtime.h>

#define N_NODES 100000
#define N_EDGES 1600000
#define D_IN 128
#define D_HID 64

#define BKT_SHIFT 7
#define BKT_NODES 128
#define NB ((N_NODES + BKT_NODES - 1) / BKT_NODES)   // 782 buckets
#define BKT_CAP 2560   // mean 2048, sigma ~45 -> +11 sigma guard

typedef __attribute__((ext_vector_type(8))) short bf16x8;
typedef __attribute__((ext_vector_type(4))) float f32x4;

__device__ __forceinline__ unsigned short f2b(float f) {
    union { float f; unsigned u; } c; c.f = f;
    unsigned r = (c.u + 0x7FFFu + ((c.u >> 16) & 1u)) >> 16;   // RNE
    return (unsigned short)r;
}
__device__ __forceinline__ float blo(unsigned u) { return __uint_as_float(u << 16); }
__device__ __forceinline__ float bhi(unsigned u) { return __uint_as_float(u & 0xffff0000u); }

// ================= init: bucket cursors + zero pad-row of h1s =================
__global__ void k_init(int* __restrict__ cursor, unsigned short* __restrict__ h1s) {
    int t = blockIdx.x * 256 + threadIdx.x;
    if (t < NB) cursor[t] = t * BKT_CAP;
    if (t < 64) h1s[(size_t)N_NODES * D_HID + t] = 0;   // pad row (index n)
}

// ================= partition edges into fixed-capacity bucket regions =================
// packed code: (src << 7) | (dst & 127); bucket = dst >> 7. 4B per edge.
__global__ __launch_bounds__(256) void k_bscatter(const int* __restrict__ src,
                                                  const int* __restrict__ dst,
                                                  int* __restrict__ cursor,
                                                  int* __restrict__ pairs, int E) {
    __shared__ int hist[NB];
    __shared__ int lbase[NB];
    __shared__ int lcur[NB];
    int chunk = (E + gridDim.x - 1) / gridDim.x;
    int beg = blockIdx.x * chunk;
    int end = min(beg + chunk, E);
    int tid = threadIdx.x;
    for (int t = tid; t < NB; t += 256) hist[t] = 0;
    __syncthreads();
    for (int e = beg + tid; e < end; e += 256)
        atomicAdd(&hist[dst[e] >> BKT_SHIFT], 1);
    __syncthreads();
    for (int t = tid; t < NB; t += 256) {
        int h = hist[t];
        lbase[t] = h ? atomicAdd(&cursor[t], h) : 0;
        lcur[t] = 0;
    }
    __syncthreads();
    for (int e = beg + tid; e < end; e += 256) {
        int d = dst[e];
        int bk = d >> BKT_SHIFT;
        int pos = lbase[bk] + atomicAdd(&lcur[bk], 1);
        if (pos < (bk + 1) * BKT_CAP)
            pairs[pos] = (src[e] << BKT_SHIFT) | (d & (BKT_NODES - 1));
    }
}

// ================= per-bucket counting sort -> CSR (padded); emits dis =================
__global__ __launch_bounds__(256) void k_bsort(const int* __restrict__ pairs,
                                               const int* __restrict__ cursor,
                                               int* __restrict__ srcs_sorted,
                                               int* __restrict__ row_start,
                                               int* __restrict__ row_end,
                                               float* __restrict__ dis, int n) {
    __shared__ int cnt[BKT_NODES];
    __shared__ int exc[BKT_NODES];
    __shared__ int sorted[BKT_CAP];
    int b = blockIdx.x;
    int base = b * BKT_CAP;
    int nE = min(cursor[b] - base, BKT_CAP);
    int node0 = b << BKT_SHIFT;
    int tid = threadIdx.x;

    if (tid < BKT_NODES) cnt[tid] = 0;
    __syncthreads();
    for (int k = tid; k < nE; k += 256)
        atomicAdd(&cnt[pairs[base + k] & (BKT_NODES - 1)], 1);
    __syncthreads();

    if (tid < 64) {   // wave-0 exclusive scan of cnt[128]
        int run = 0;
        for (int c = 0; c < BKT_NODES; c += 64) {
            int v = cnt[c + tid];
            int inc = v;
            for (int off = 1; off < 64; off <<= 1) {
                int t2 = __shfl_up(inc, off);
                if (tid >= off) inc += t2;
            }
            exc[c + tid] = run + inc - v;
            run += __shfl(inc, 63);
        }
    }
    __syncthreads();

    if (tid < BKT_NODES) {
        int node = node0 + tid;
        if (node < n) {
            int rs = base + exc[tid];
            row_start[node] = rs;
            row_end[node] = rs + cnt[tid];
            dis[node] = rsqrtf((float)cnt[tid] + 1.0f);
        }
    }
    __syncthreads();
    if (tid < BKT_NODES) cnt[tid] = exc[tid];
    __syncthreads();

    for (int k = tid; k < nE; k += 256) {
        int pk = pairs[base + k];
        int pos = atomicAdd(&cnt[pk & (BKT_NODES - 1)], 1);
        sorted[pos] = pk >> BKT_SHIFT;       // src id
    }
    __syncthreads();
    for (int k = tid; k < nE; k += 256)
        srcs_sorted[base + k] = sorted[k];
}

// ================= layer 1 GEMM via bf16 MFMA, epilogue pre-scales by dis =================
// h1s[node][f] = bf16( dis[node] * (x @ W1)[node][f] )
#define LS 136
__global__ __launch_bounds__(256) void k_gemm1(const float* __restrict__ x,
                                               const float* __restrict__ W1,
                                               const float* __restrict__ dis,
                                               unsigned short* __restrict__ h1s, int n) {
    __shared__ unsigned short xs[64 * LS];
    __shared__ unsigned short ws[64 * LS];
    int tid = threadIdx.x;
    int node0 = blockIdx.x * 64;

    for (int i = 0; i < 32; ++i) {
        int e = tid + i * 256;
        int k = e >> 6, f = e & 63;
        ws[f * LS + k] = f2b(W1[e]);
    }
    for (int i = 0; i < 8; ++i) {
        int e4 = tid + i * 256;
        int node = e4 >> 5;
        int k = (e4 & 31) * 4;
        float4 v = make_float4(0.f, 0.f, 0.f, 0.f);
        if (node0 + node < n)
            v = ((const float4*)x)[((size_t)(node0 + node) * D_IN + k) >> 2];
        unsigned short* p = &xs[node * LS + k];
        p[0] = f2b(v.x); p[1] = f2b(v.y); p[2] = f2b(v.z); p[3] = f2b(v.w);
    }
    __syncthreads();

    int wv = tid >> 6;
    int lane = tid & 63;
    int m16 = lane & 15;
    int q = lane >> 4;

    bf16x8 afrag[4];
#pragma unroll
    for (int ks = 0; ks < 4; ++ks)
        afrag[ks] = *(const bf16x8*)&xs[(wv * 16 + m16) * LS + ks * 32 + q * 8];

    f32x4 acc[4];
#pragma unroll
    for (int ft = 0; ft < 4; ++ft) acc[ft] = (f32x4){0.f, 0.f, 0.f, 0.f};

#pragma unroll
    for (int ft = 0; ft < 4; ++ft)
#pragma unroll
        for (int ks = 0; ks < 4; ++ks) {
            bf16x8 bfrag = *(const bf16x8*)&ws[(ft * 16 + m16) * LS + ks * 32 + q * 8];
            acc[ft] = __builtin_amdgcn_mfma_f32_16x16x32_bf16(afrag[ks], bfrag, acc[ft], 0, 0, 0);
        }

#pragma unroll
    for (int r = 0; r < 4; ++r) {
        int node = node0 + wv * 16 + q * 4 + r;
        if (node < n) {
            float d = dis[node];
#pragma unroll
            for (int ft = 0; ft < 4; ++ft)
                h1s[(size_t)node * D_HID + ft * 16 + m16] = f2b(acc[ft][r] * d);
        }
    }
}

// ================= fused agg1 + bias + ReLU + dot(W2) -> zd = z*dis =================
// One wave per dst node; 8 edges/iter (8 lanes each, uint4 = 8 bf16 feats/lane).
// h1s pre-scaled by dis[src] -> loop is pure unpack+add. Padded slots -> zero row n.
__global__ __launch_bounds__(256) void k_gather1(const int* __restrict__ srcs,
                                                 const int* __restrict__ row_start,
                                                 const int* __restrict__ row_end,
                                                 const float* __restrict__ dis,
                                                 const uint4* __restrict__ h4,
                                                 const float* __restrict__ b1,
                                                 const float* __restrict__ W2,
                                                 float* __restrict__ zd, int n) {
    int i = blockIdx.x * 4 + (threadIdx.x >> 6);
    if (i >= n) return;
    int lane = threadIdx.x & 63;
    int g = lane >> 3;        // edge slot within iteration
    int m8 = lane & 7;        // feature block (feats 8*m8 .. 8*m8+7)
    float dd = dis[i];

    float a0 = 0.f, a1 = 0.f, a2 = 0.f, a3 = 0.f, a4 = 0.f, a5 = 0.f, a6 = 0.f, a7 = 0.f;
    if (g == 0) {             // self-loop: + h1s[i]  (h1s[i] = dis_i*h_i, and dd*h1s[i] = dd^2*h_i)
        uint4 u = h4[(unsigned)i * 8u + m8];
        a0 = blo(u.x); a1 = bhi(u.x);
        a2 = blo(u.y); a3 = bhi(u.y);
        a4 = blo(u.z); a5 = bhi(u.z);
        a6 = blo(u.w); a7 = bhi(u.w);
    }

    int beg = row_start[i], end = row_end[i];
    for (int jb = beg; jb < end; jb += 64) {
        int m = min(64, end - jb);
        int sv = (lane < m) ? srcs[jb + lane] : n;   // pad -> zero row
        int pmax = (m + 7) >> 3;
#pragma unroll 4
        for (int p = 0; p < pmax; ++p) {
            int s = __shfl(sv, p * 8 + g);
            uint4 u = h4[(unsigned)s * 8u + m8];
            a0 += blo(u.x); a1 += bhi(u.x);
            a2 += blo(u.y); a3 += bhi(u.y);
            a4 += blo(u.z); a5 += bhi(u.z);
            a6 += blo(u.w); a7 += bhi(u.w);
        }
    }

    // reduce across the 8 edge-groups (lane bits 3..5)
#pragma unroll
    for (int off = 8; off < 64; off <<= 1) {
        a0 += __shfl_xor(a0, off); a1 += __shfl_xor(a1, off);
        a2 += __shfl_xor(a2, off); a3 += __shfl_xor(a3, off);
        a4 += __shfl_xor(a4, off); a5 += __shfl_xor(a5, off);
        a6 += __shfl_xor(a6, off); a7 += __shfl_xor(a7, off);
    }
    float4 ba = ((const float4*)b1)[m8 * 2];
    float4 bb = ((const float4*)b1)[m8 * 2 + 1];
    float4 wa = ((const float4*)W2)[m8 * 2];
    float4 wb = ((const float4*)W2)[m8 * 2 + 1];
    float v = fmaxf(fmaf(dd, a0, ba.x), 0.f) * wa.x + fmaxf(fmaf(dd, a1, ba.y), 0.f) * wa.y
            + fmaxf(fmaf(dd, a2, ba.z), 0.f) * wa.z + fmaxf(fmaf(dd, a3, ba.w), 0.f) * wa.w
            + fmaxf(fmaf(dd, a4, bb.x), 0.f) * wb.x + fmaxf(fmaf(dd, a5, bb.y), 0.f) * wb.y
            + fmaxf(fmaf(dd, a6, bb.z), 0.f) * wb.z + fmaxf(fmaf(dd, a7, bb.w), 0.f) * wb.w;
#pragma unroll
    for (int off = 1; off < 8; off <<= 1) v += __shfl_xor(v, off);
    if (lane == 0) zd[i] = v * dd;
}

// ================= agg2 (lane-parallel) + fused padded output =================
__global__ __launch_bounds__(256) void k_gather2(const int* __restrict__ srcs,
                                                 const int* __restrict__ row_start,
                                                 const int* __restrict__ row_end,
                                                 const float* __restrict__ dis,
                                                 const float* __restrict__ zd,
                                                 const float* __restrict__ b2,
                                                 float* __restrict__ out, int n) {
    int i = blockIdx.x * 4 + (threadIdx.x >> 6);
    if (i >= n) return;
    int lane = threadIdx.x & 63;
    float acc = 0.f;
    int beg = row_start[i], end = row_end[i];
    for (int j = beg + lane; j < end; j += 64)
        acc += zd[srcs[j]];
#pragma unroll
    for (int off = 32; off > 0; off >>= 1) acc += __shfl_xor(acc, off);
    float y = (acc + zd[i]) * dis[i] + b2[0];
    float2 v = (lane == 0) ? make_float2(y, 0.f) : make_float2(0.f, 0.f);
    ((float2*)out)[(size_t)i * 64 + lane] = v;
}

extern "C" void kernel_launch(void* const* d_in, const int* in_sizes, int n_in,
                              void* d_out, int out_size, void* d_ws, size_t ws_size,
                              hipStream_t stream) {
    const float* x  = (const float*)d_in[0];
    const int*   ei = (const int*)d_in[1];   // [2, E] int32
    const float* W1 = (const float*)d_in[2];
    const float* b1 = (const float*)d_in[3];
    const float* W2 = (const float*)d_in[4];
    const float* b2 = (const float*)d_in[5];
    float* out = (float*)d_out;

    const int n = N_NODES;
    const int E = N_EDGES;
    const int* src = ei;
    const int* dst = ei + E;

    // ws: pairs int[NB*CAP] | srcs_sorted int[NB*CAP] | row_start[n] | row_end[n]
    //     | cursor[NB] | dis f[n] | h1s ushort[(n+1)*64] | zd f[n]   (~31 MB)
    int* pairs       = (int*)d_ws;
    int* srcs_sorted = pairs + (size_t)NB * BKT_CAP;
    int* row_start   = srcs_sorted + (size_t)NB * BKT_CAP;
    int* row_end     = row_start + n;
    int* cursor      = row_end + n;
    float* dis       = (float*)(cursor + NB);
    unsigned short* h1s = (unsigned short*)(dis + n);
    float* zd        = (float*)(h1s + (size_t)(n + 1) * D_HID);

    k_init<<<(NB + 255) / 256, 256, 0, stream>>>(cursor, h1s);
    k_bscatter<<<784, 256, 0, stream>>>(src, dst, cursor, pairs, E);
    k_bsort<<<NB, 256, 0, stream>>>(pairs, cursor, srcs_sorted, row_start, row_end, dis, n);

    k_gemm1<<<(n + 63) / 64, 256, 0, stream>>>(x, W1, dis, h1s, n);

    k_gather1<<<(n + 3) / 4, 256, 0, stream>>>(srcs_sorted, row_start, row_end, dis,
                                               (const uint4*)h1s, b1, W2, zd, n);
    k_gather2<<<(n + 3) / 4, 256, 0, stream>>>(srcs_sorted, row_start, row_end, dis,
                                               zd, b2, out, n);
}

// Round 9
// 228.562 us; speedup vs baseline: 1.4364x; 1.0418x over previous
//
#include <hip/hip_runtime.h>

#define N_NODES 100000
#define N_EDGES 1600000
#define D_IN 128
#define D_HID 64

#define BKT_SHIFT 7
#define BKT_NODES 128
#define NB ((N_NODES + BKT_NODES - 1) / BKT_NODES)   // 782 buckets
#define BKT_CAP 2560   // mean 2048 edges/bucket, +11 sigma guard

typedef __attribute__((ext_vector_type(8))) short bf16x8;
typedef __attribute__((ext_vector_type(4))) float f32x4;

__device__ __forceinline__ unsigned short f2b(float f) {
    union { float f; unsigned u; } c; c.f = f;
    unsigned r = (c.u + 0x7FFFu + ((c.u >> 16) & 1u)) >> 16;   // RNE
    return (unsigned short)r;
}
__device__ __forceinline__ float blo(unsigned u) { return __uint_as_float(u << 16); }
__device__ __forceinline__ float bhi(unsigned u) { return __uint_as_float(u & 0xffff0000u); }

// ================= prep: cursors + W1 -> bf16 transposed [64][128] =================
__global__ __launch_bounds__(256) void k_prep(const float* __restrict__ W1,
                                              unsigned short* __restrict__ w1t,
                                              int* __restrict__ cursor) {
    int t = blockIdx.x * 256 + threadIdx.x;          // 8192 threads
    if (t < NB) cursor[t] = t * BKT_CAP;
    int k = t >> 6, f = t & 63;                      // W1 is [128][64]
    w1t[f * D_IN + k] = f2b(W1[t]);
}

// ================= partition edges into fixed-capacity bucket regions =================
// packed code: (src << 7) | (dst & 127); bucket = dst >> 7. 4B per edge.
__global__ __launch_bounds__(256) void k_bscatter(const int* __restrict__ src,
                                                  const int* __restrict__ dst,
                                                  int* __restrict__ cursor,
                                                  int* __restrict__ pairs, int E) {
    __shared__ int hist[NB];
    __shared__ int lbase[NB];
    __shared__ int lcur[NB];
    int chunk = (E + gridDim.x - 1) / gridDim.x;
    int beg = blockIdx.x * chunk;
    int end = min(beg + chunk, E);
    int tid = threadIdx.x;
    for (int t = tid; t < NB; t += 256) hist[t] = 0;
    __syncthreads();
    for (int e = beg + tid; e < end; e += 256)
        atomicAdd(&hist[dst[e] >> BKT_SHIFT], 1);
    __syncthreads();
    for (int t = tid; t < NB; t += 256) {
        int h = hist[t];
        lbase[t] = h ? atomicAdd(&cursor[t], h) : 0;
        lcur[t] = 0;
    }
    __syncthreads();
    for (int e = beg + tid; e < end; e += 256) {
        int d = dst[e];
        int bk = d >> BKT_SHIFT;
        int pos = lbase[bk] + atomicAdd(&lcur[bk], 1);
        if (pos < (bk + 1) * BKT_CAP)
            pairs[pos] = (src[e] << BKT_SHIFT) | (d & (BKT_NODES - 1));
    }
}

// ================= per-bucket counting sort -> CSR (padded); emits dis =================
__global__ __launch_bounds__(256) void k_bsort(const int* __restrict__ pairs,
                                               const int* __restrict__ cursor,
                                               int* __restrict__ srcs_sorted,
                                               int* __restrict__ row_start,
                                               int* __restrict__ row_end,
                                               float* __restrict__ dis, int n) {
    __shared__ int cnt[BKT_NODES];
    __shared__ int exc[BKT_NODES];
    __shared__ int sorted[BKT_CAP];
    int b = blockIdx.x;
    int base = b * BKT_CAP;
    int nE = min(cursor[b] - base, BKT_CAP);
    int node0 = b << BKT_SHIFT;
    int tid = threadIdx.x;

    if (tid < BKT_NODES) cnt[tid] = 0;
    __syncthreads();
    for (int k = tid; k < nE; k += 256)
        atomicAdd(&cnt[pairs[base + k] & (BKT_NODES - 1)], 1);
    __syncthreads();

    if (tid < 64) {   // wave-0 exclusive scan of cnt[128]
        int run = 0;
        for (int c = 0; c < BKT_NODES; c += 64) {
            int v = cnt[c + tid];
            int inc = v;
            for (int off = 1; off < 64; off <<= 1) {
                int t2 = __shfl_up(inc, off);
                if (tid >= off) inc += t2;
            }
            exc[c + tid] = run + inc - v;
            run += __shfl(inc, 63);
        }
    }
    __syncthreads();

    if (tid < BKT_NODES) {
        int node = node0 + tid;
        if (node < n) {
            int rs = base + exc[tid];
            row_start[node] = rs;
            row_end[node] = rs + cnt[tid];
            dis[node] = rsqrtf((float)cnt[tid] + 1.0f);
        }
    }
    __syncthreads();
    if (tid < BKT_NODES) cnt[tid] = exc[tid];
    __syncthreads();

    for (int k = tid; k < nE; k += 256) {
        int pk = pairs[base + k];
        int pos = atomicAdd(&cnt[pk & (BKT_NODES - 1)], 1);
        sorted[pos] = pk >> BKT_SHIFT;       // src id
    }
    __syncthreads();
    for (int k = tid; k < nE; k += 256)
        srcs_sorted[base + k] = sorted[k];
}

// ================= layer 1 GEMM via bf16 MFMA, epilogue pre-scales by dis ===========
// h1s[node][f] = bf16( dis[node] * (x @ W1)[node][f] );  W1 comes pre-converted (w1t)
#define LS 136
__global__ __launch_bounds__(256) void k_gemm1(const float* __restrict__ x,
                                               const uint4* __restrict__ w1t4,
                                               const float* __restrict__ dis,
                                               unsigned short* __restrict__ h1s, int n) {
    __shared__ unsigned short xs[64 * LS];
    __shared__ unsigned short ws[64 * LS];
    int tid = threadIdx.x;
    int node0 = blockIdx.x * 64;

    // stage pre-converted W1^T: 64 rows x 128 bf16 = 1024 uint4
#pragma unroll
    for (int it = 0; it < 4; ++it) {
        int e = tid + it * 256;
        int f = e >> 4, c = e & 15;
        *(uint4*)&ws[f * LS + c * 8] = w1t4[e];
    }
    // stage x tile: 64 rows x 128 fp32 -> bf16, packed 8B LDS writes
#pragma unroll
    for (int it = 0; it < 8; ++it) {
        int e4 = tid + it * 256;
        int node = e4 >> 5;
        int k = (e4 & 31) * 4;
        float4 v = make_float4(0.f, 0.f, 0.f, 0.f);
        if (node0 + node < n)
            v = ((const float4*)x)[((size_t)(node0 + node) * D_IN + k) >> 2];
        uint2 u;
        u.x = (unsigned)f2b(v.x) | ((unsigned)f2b(v.y) << 16);
        u.y = (unsigned)f2b(v.z) | ((unsigned)f2b(v.w) << 16);
        *(uint2*)&xs[node * LS + k] = u;
    }
    __syncthreads();

    int wv = tid >> 6;
    int lane = tid & 63;
    int m16 = lane & 15;
    int q = lane >> 4;

    bf16x8 afrag[4];
#pragma unroll
    for (int ks = 0; ks < 4; ++ks)
        afrag[ks] = *(const bf16x8*)&xs[(wv * 16 + m16) * LS + ks * 32 + q * 8];

    f32x4 acc[4];
#pragma unroll
    for (int ft = 0; ft < 4; ++ft) acc[ft] = (f32x4){0.f, 0.f, 0.f, 0.f};

#pragma unroll
    for (int ft = 0; ft < 4; ++ft)
#pragma unroll
        for (int ks = 0; ks < 4; ++ks) {
            bf16x8 bfrag = *(const bf16x8*)&ws[(ft * 16 + m16) * LS + ks * 32 + q * 8];
            acc[ft] = __builtin_amdgcn_mfma_f32_16x16x32_bf16(afrag[ks], bfrag, acc[ft], 0, 0, 0);
        }

#pragma unroll
    for (int r = 0; r < 4; ++r) {
        int node = node0 + wv * 16 + q * 4 + r;
        if (node < n) {
            float d = dis[node];
#pragma unroll
            for (int ft = 0; ft < 4; ++ft)
                h1s[(size_t)node * D_HID + ft * 16 + m16] = f2b(acc[ft][r] * d);
        }
    }
}

// ================= fused agg1 + bias + ReLU + dot(W2) -> zd = z*dis =================
// 2 dst nodes per wave (32 lanes each: 4 edge-groups x 8 feat-lanes).
// Direct broadcast loads of srcs[j] (8 lanes same addr), unroll x2 for MLP.
// h1s pre-scaled by dis[src] -> loop body is pure unpack+add.
__global__ __launch_bounds__(256) void k_gather1(const int* __restrict__ srcs,
                                                 const int* __restrict__ row_start,
                                                 const int* __restrict__ row_end,
                                                 const float* __restrict__ dis,
                                                 const uint4* __restrict__ h4,
                                                 const float* __restrict__ b1,
                                                 const float* __restrict__ W2,
                                                 float* __restrict__ zd, int n) {
    int i = blockIdx.x * 8 + (threadIdx.x >> 5);     // node for this half-wave
    int lane = threadIdx.x & 63;
    int g = (lane >> 3) & 3;  // edge group within half-wave
    int m8 = lane & 7;        // feature block (feats 8*m8 .. 8*m8+7)
    float dd = dis[i];

    float a0, a1, a2, a3, a4, a5, a6, a7;
    {   // self-loop handled by group 0
        uint4 u = h4[(unsigned)i * 8u + m8];
        float w = (g == 0) ? 1.f : 0.f;
        a0 = w * blo(u.x); a1 = w * bhi(u.x);
        a2 = w * blo(u.y); a3 = w * bhi(u.y);
        a4 = w * blo(u.z); a5 = w * bhi(u.z);
        a6 = w * blo(u.w); a7 = w * bhi(u.w);
    }

#define ACC(u) { a0 += blo(u.x); a1 += bhi(u.x); a2 += blo(u.y); a3 += bhi(u.y); \
                 a4 += blo(u.z); a5 += bhi(u.z); a6 += blo(u.w); a7 += bhi(u.w); }
    int end = row_end[i];
    int j = row_start[i] + g;
    for (; j + 4 < end; j += 8) {               // unroll x2: two loads in flight
        int s0 = srcs[j];
        int s1 = srcs[j + 4];
        uint4 u0 = h4[(unsigned)s0 * 8u + m8];
        uint4 u1 = h4[(unsigned)s1 * 8u + m8];
        ACC(u0); ACC(u1);
    }
    if (j < end) {
        int s0 = srcs[j];
        uint4 u0 = h4[(unsigned)s0 * 8u + m8];
        ACC(u0);
    }
#undef ACC

    // combine the 4 edge-groups within each half-wave (lane bits 3,4)
#pragma unroll
    for (int off = 8; off < 32; off <<= 1) {
        a0 += __shfl_xor(a0, off); a1 += __shfl_xor(a1, off);
        a2 += __shfl_xor(a2, off); a3 += __shfl_xor(a3, off);
        a4 += __shfl_xor(a4, off); a5 += __shfl_xor(a5, off);
        a6 += __shfl_xor(a6, off); a7 += __shfl_xor(a7, off);
    }
    float4 ba = ((const float4*)b1)[m8 * 2];
    float4 bb = ((const float4*)b1)[m8 * 2 + 1];
    float4 wa = ((const float4*)W2)[m8 * 2];
    float4 wb = ((const float4*)W2)[m8 * 2 + 1];
    float v = fmaxf(fmaf(dd, a0, ba.x), 0.f) * wa.x + fmaxf(fmaf(dd, a1, ba.y), 0.f) * wa.y
            + fmaxf(fmaf(dd, a2, ba.z), 0.f) * wa.z + fmaxf(fmaf(dd, a3, ba.w), 0.f) * wa.w
            + fmaxf(fmaf(dd, a4, bb.x), 0.f) * wb.x + fmaxf(fmaf(dd, a5, bb.y), 0.f) * wb.y
            + fmaxf(fmaf(dd, a6, bb.z), 0.f) * wb.z + fmaxf(fmaf(dd, a7, bb.w), 0.f) * wb.w;
#pragma unroll
    for (int off = 1; off < 8; off <<= 1) v += __shfl_xor(v, off);
    if ((lane & 31) == 0) zd[i] = v * dd;
}

// ================= agg2 (2 nodes/wave) + fused padded output =================
__global__ __launch_bounds__(256) void k_gather2(const int* __restrict__ srcs,
                                                 const int* __restrict__ row_start,
                                                 const int* __restrict__ row_end,
                                                 const float* __restrict__ dis,
                                                 const float* __restrict__ zd,
                                                 const float* __restrict__ b2,
                                                 float* __restrict__ out, int n) {
    int i = blockIdx.x * 8 + (threadIdx.x >> 5);
    int l = threadIdx.x & 31;
    float acc = 0.f;
    int beg = row_start[i], end = row_end[i];
    for (int j = beg + l; j < end; j += 32)
        acc += zd[srcs[j]];
#pragma unroll
    for (int off = 1; off < 32; off <<= 1) acc += __shfl_xor(acc, off);
    float y = (acc + zd[i]) * dis[i] + b2[0];
    float4 v = make_float4(0.f, 0.f, 0.f, 0.f);
    if (l == 0) v.x = y;
    ((float4*)out)[(size_t)i * 32 + l] = v;
}

extern "C" void kernel_launch(void* const* d_in, const int* in_sizes, int n_in,
                              void* d_out, int out_size, void* d_ws, size_t ws_size,
                              hipStream_t stream) {
    const float* x  = (const float*)d_in[0];
    const int*   ei = (const int*)d_in[1];   // [2, E] int32
    const float* W1 = (const float*)d_in[2];
    const float* b1 = (const float*)d_in[3];
    const float* W2 = (const float*)d_in[4];
    const float* b2 = (const float*)d_in[5];
    float* out = (float*)d_out;

    const int n = N_NODES;
    const int E = N_EDGES;
    const int* src = ei;
    const int* dst = ei + E;

    // ws: pairs int[NB*CAP] | srcs_sorted int[NB*CAP] | row_start[n] | row_end[n]
    //     | cursor[NB] | dis f[n] | h1s ushort[n*64] | w1t ushort[8192] | zd f[n]
    int* pairs       = (int*)d_ws;
    int* srcs_sorted = pairs + (size_t)NB * BKT_CAP;
    int* row_start   = srcs_sorted + (size_t)NB * BKT_CAP;
    int* row_end     = row_start + n;
    int* cursor      = row_end + n;
    float* dis       = (float*)(cursor + ((NB + 3) & ~3));
    unsigned short* h1s = (unsigned short*)(dis + n);
    unsigned short* w1t = h1s + (size_t)n * D_HID;
    float* zd        = (float*)(w1t + D_IN * D_HID);

    k_prep<<<32, 256, 0, stream>>>(W1, w1t, cursor);
    k_bscatter<<<784, 256, 0, stream>>>(src, dst, cursor, pairs, E);
    k_bsort<<<NB, 256, 0, stream>>>(pairs, cursor, srcs_sorted, row_start, row_end, dis, n);

    k_gemm1<<<(n + 63) / 64, 256, 0, stream>>>(x, (const uint4*)w1t, dis, h1s, n);

    k_gather1<<<(n + 7) / 8, 256, 0, stream>>>(srcs_sorted, row_start, row_end, dis,
                                               (const uint4*)h1s, b1, W2, zd, n);
    k_gather2<<<(n + 7) / 8, 256, 0, stream>>>(srcs_sorted, row_start, row_end, dis,
                                               zd, b2, out, n);
}

// Round 10
// 226.349 us; speedup vs baseline: 1.4504x; 1.0098x over previous
//
#include <hip/hip_runtime.h>

#define N_NODES 100000
#define N_EDGES 1600000
#define D_IN 128
#define D_HID 64

#define BKT_SHIFT 8
#define BKT_NODES 256
#define NB 391          // ceil(N_NODES / 256)
#define NBLK 784        // scatter blocks
#define SLOT 16         // slots per (block,bucket); Poisson(5.2) + ~11 sigma
#define BKT_CAP 5120    // per-bucket capacity in srcs_sorted (mean 4092, +16 sigma)
#define OVF_CAP 8192

typedef __attribute__((ext_vector_type(8))) short bf16x8;
typedef __attribute__((ext_vector_type(4))) float f32x4;

__device__ __forceinline__ unsigned short f2b(float f) {
    union { float f; unsigned u; } c; c.f = f;
    unsigned r = (c.u + 0x7FFFu + ((c.u >> 16) & 1u)) >> 16;   // RNE
    return (unsigned short)r;
}
__device__ __forceinline__ float blo(unsigned u) { return __uint_as_float(u << 16); }
__device__ __forceinline__ float bhi(unsigned u) { return __uint_as_float(u & 0xffff0000u); }

// ================= prep: W1 -> bf16 transposed + zero overflow counter =================
__global__ __launch_bounds__(256) void k_prep(const float* __restrict__ W1,
                                              unsigned short* __restrict__ w1t,
                                              int* __restrict__ ovf_cnt) {
    int t = blockIdx.x * 256 + threadIdx.x;          // 8192 threads
    if (t == 0) ovf_cnt[0] = 0;
    int k = t >> 6, f = t & 63;                      // W1 is [128][64]
    w1t[f * D_IN + k] = f2b(W1[t]);
}

// ================= one-pass partition into per-(block,bucket) slot regions ==========
// code = (src << 8) | (dst & 255); region pairs_blk[block][bucket][SLOT]
__global__ __launch_bounds__(256) void k_escatter(const int* __restrict__ src,
                                                  const int* __restrict__ dst,
                                                  int* __restrict__ pairs_blk,
                                                  int* __restrict__ cnt_blk,
                                                  int* __restrict__ ovf_cnt,
                                                  int2* __restrict__ ovf, int E) {
    __shared__ int lcur[NB];
    int tid = threadIdx.x;
    for (int t = tid; t < NB; t += 256) lcur[t] = 0;
    __syncthreads();
    int chunk = (E + NBLK - 1) / NBLK;
    int beg = blockIdx.x * chunk;
    int end = min(beg + chunk, E);
    int rbase = blockIdx.x * NB * SLOT;
    for (int e = beg + tid; e < end; e += 256) {
        int d = dst[e], s = src[e];
        int bk = d >> BKT_SHIFT;
        int slot = atomicAdd(&lcur[bk], 1);
        if (slot < SLOT)
            pairs_blk[rbase + bk * SLOT + slot] = (s << BKT_SHIFT) | (d & (BKT_NODES - 1));
        else {
            int o = atomicAdd(ovf_cnt, 1);
            if (o < OVF_CAP) ovf[o] = make_int2(s, d);
        }
    }
    __syncthreads();
    for (int t = tid; t < NB; t += 256)
        cnt_blk[t * NBLK + blockIdx.x] = min(lcur[t], SLOT);   // [bucket][block]
}

// ================= per-bucket sort: histogram -> scan -> place; emits CSR + dis =======
__global__ __launch_bounds__(256) void k_bsort(const int* __restrict__ pairs_blk,
                                               const int* __restrict__ cnt_blk,
                                               const int* __restrict__ ovf_cnt,
                                               const int2* __restrict__ ovf,
                                               int* __restrict__ srcs_sorted,
                                               int* __restrict__ row_start,
                                               int* __restrict__ row_end,
                                               float* __restrict__ dis, int n) {
    __shared__ int segc[NBLK];
    __shared__ int cnt[BKT_NODES];
    __shared__ int exc[BKT_NODES];
    int b = blockIdx.x;
    int tid = threadIdx.x;
    int node0 = b << BKT_SHIFT;
    int ocnt = min(ovf_cnt[0], OVF_CAP);

    for (int i = tid; i < NBLK; i += 256) segc[i] = cnt_blk[b * NBLK + i];
    cnt[tid] = 0;
    __syncthreads();

    // histogram over the bucket's 256 nodes
    for (int i = tid; i < NBLK; i += 256) {
        int c = segc[i];
        const int* p = &pairs_blk[(i * NB + b) * SLOT];
        for (int k = 0; k < c; ++k)
            atomicAdd(&cnt[p[k] & (BKT_NODES - 1)], 1);
    }
    for (int k = tid; k < ocnt; k += 256) {
        int2 e = ovf[k];
        if ((e.y >> BKT_SHIFT) == b) atomicAdd(&cnt[e.y & (BKT_NODES - 1)], 1);
    }
    __syncthreads();

    if (tid < 64) {   // wave-0 exclusive scan of cnt[256]
        int run = 0;
        for (int c = 0; c < BKT_NODES; c += 64) {
            int v = cnt[c + tid];
            int inc = v;
            for (int off = 1; off < 64; off <<= 1) {
                int t2 = __shfl_up(inc, off);
                if (tid >= off) inc += t2;
            }
            exc[c + tid] = run + inc - v;
            run += __shfl(inc, 63);
        }
    }
    __syncthreads();

    int node = node0 + tid;
    if (node < n) {
        int rs = b * BKT_CAP + exc[tid];
        row_start[node] = rs;
        row_end[node] = rs + cnt[tid];
        dis[node] = rsqrtf((float)cnt[tid] + 1.0f);
    }
    __syncthreads();
    cnt[tid] = exc[tid];          // repurpose as per-node cursor
    __syncthreads();

    // place pass (segments are L2-hot from the histogram pass)
    int gbase = b * BKT_CAP;
    for (int i = tid; i < NBLK; i += 256) {
        int c = segc[i];
        const int* p = &pairs_blk[(i * NB + b) * SLOT];
        for (int k = 0; k < c; ++k) {
            int pk = p[k];
            int pos = atomicAdd(&cnt[pk & (BKT_NODES - 1)], 1);
            srcs_sorted[gbase + pos] = pk >> BKT_SHIFT;
        }
    }
    for (int k = tid; k < ocnt; k += 256) {
        int2 e = ovf[k];
        if ((e.y >> BKT_SHIFT) == b) {
            int pos = atomicAdd(&cnt[e.y & (BKT_NODES - 1)], 1);
            srcs_sorted[gbase + pos] = e.x;
        }
    }
}

// ================= layer 1 GEMM via bf16 MFMA, epilogue pre-scales by dis ===========
// h1s[node][f] = bf16( dis[node] * (x @ W1)[node][f] )
#define LS 136
__global__ __launch_bounds__(256) void k_gemm1(const float* __restrict__ x,
                                               const uint4* __restrict__ w1t4,
                                               const float* __restrict__ dis,
                                               unsigned short* __restrict__ h1s, int n) {
    __shared__ unsigned short xs[64 * LS];
    __shared__ unsigned short ws[64 * LS];
    int tid = threadIdx.x;
    int node0 = blockIdx.x * 64;

#pragma unroll
    for (int it = 0; it < 4; ++it) {
        int e = tid + it * 256;
        int f = e >> 4, c = e & 15;
        *(uint4*)&ws[f * LS + c * 8] = w1t4[e];
    }
#pragma unroll
    for (int it = 0; it < 8; ++it) {
        int e4 = tid + it * 256;
        int node = e4 >> 5;
        int k = (e4 & 31) * 4;
        float4 v = make_float4(0.f, 0.f, 0.f, 0.f);
        if (node0 + node < n)
            v = ((const float4*)x)[((size_t)(node0 + node) * D_IN + k) >> 2];
        uint2 u;
        u.x = (unsigned)f2b(v.x) | ((unsigned)f2b(v.y) << 16);
        u.y = (unsigned)f2b(v.z) | ((unsigned)f2b(v.w) << 16);
        *(uint2*)&xs[node * LS + k] = u;
    }
    __syncthreads();

    int wv = tid >> 6;
    int lane = tid & 63;
    int m16 = lane & 15;
    int q = lane >> 4;

    bf16x8 afrag[4];
#pragma unroll
    for (int ks = 0; ks < 4; ++ks)
        afrag[ks] = *(const bf16x8*)&xs[(wv * 16 + m16) * LS + ks * 32 + q * 8];

    f32x4 acc[4];
#pragma unroll
    for (int ft = 0; ft < 4; ++ft) acc[ft] = (f32x4){0.f, 0.f, 0.f, 0.f};

#pragma unroll
    for (int ft = 0; ft < 4; ++ft)
#pragma unroll
        for (int ks = 0; ks < 4; ++ks) {
            bf16x8 bfrag = *(const bf16x8*)&ws[(ft * 16 + m16) * LS + ks * 32 + q * 8];
            acc[ft] = __builtin_amdgcn_mfma_f32_16x16x32_bf16(afrag[ks], bfrag, acc[ft], 0, 0, 0);
        }

#pragma unroll
    for (int r = 0; r < 4; ++r) {
        int node = node0 + wv * 16 + q * 4 + r;
        if (node < n) {
            float d = dis[node];
#pragma unroll
            for (int ft = 0; ft < 4; ++ft)
                h1s[(size_t)node * D_HID + ft * 16 + m16] = f2b(acc[ft][r] * d);
        }
    }
}

// ================= fused agg1 + bias + ReLU + dot(W2) -> zd = z*dis =================
// 2 dst nodes per wave (32 lanes each: 4 edge-groups x 8 feat-lanes), unroll x2.
__global__ __launch_bounds__(256) void k_gather1(const int* __restrict__ srcs,
                                                 const int* __restrict__ row_start,
                                                 const int* __restrict__ row_end,
                                                 const float* __restrict__ dis,
                                                 const uint4* __restrict__ h4,
                                                 const float* __restrict__ b1,
                                                 const float* __restrict__ W2,
                                                 float* __restrict__ zd, int n) {
    int i = blockIdx.x * 8 + (threadIdx.x >> 5);     // node for this half-wave
    int lane = threadIdx.x & 63;
    int g = (lane >> 3) & 3;  // edge group within half-wave
    int m8 = lane & 7;        // feature block (feats 8*m8 .. 8*m8+7)
    float dd = dis[i];

    float a0, a1, a2, a3, a4, a5, a6, a7;
    {   // self-loop handled by group 0
        uint4 u = h4[(unsigned)i * 8u + m8];
        float w = (g == 0) ? 1.f : 0.f;
        a0 = w * blo(u.x); a1 = w * bhi(u.x);
        a2 = w * blo(u.y); a3 = w * bhi(u.y);
        a4 = w * blo(u.z); a5 = w * bhi(u.z);
        a6 = w * blo(u.w); a7 = w * bhi(u.w);
    }

#define ACC(u) { a0 += blo(u.x); a1 += bhi(u.x); a2 += blo(u.y); a3 += bhi(u.y); \
                 a4 += blo(u.z); a5 += bhi(u.z); a6 += blo(u.w); a7 += bhi(u.w); }
    int end = row_end[i];
    int j = row_start[i] + g;
    for (; j + 4 < end; j += 8) {               // unroll x2: two loads in flight
        int s0 = srcs[j];
        int s1 = srcs[j + 4];
        uint4 u0 = h4[(unsigned)s0 * 8u + m8];
        uint4 u1 = h4[(unsigned)s1 * 8u + m8];
        ACC(u0); ACC(u1);
    }
    if (j < end) {
        int s0 = srcs[j];
        uint4 u0 = h4[(unsigned)s0 * 8u + m8];
        ACC(u0);
    }
#undef ACC

#pragma unroll
    for (int off = 8; off < 32; off <<= 1) {
        a0 += __shfl_xor(a0, off); a1 += __shfl_xor(a1, off);
        a2 += __shfl_xor(a2, off); a3 += __shfl_xor(a3, off);
        a4 += __shfl_xor(a4, off); a5 += __shfl_xor(a5, off);
        a6 += __shfl_xor(a6, off); a7 += __shfl_xor(a7, off);
    }
    float4 ba = ((const float4*)b1)[m8 * 2];
    float4 bb = ((const float4*)b1)[m8 * 2 + 1];
    float4 wa = ((const float4*)W2)[m8 * 2];
    float4 wb = ((const float4*)W2)[m8 * 2 + 1];
    float v = fmaxf(fmaf(dd, a0, ba.x), 0.f) * wa.x + fmaxf(fmaf(dd, a1, ba.y), 0.f) * wa.y
            + fmaxf(fmaf(dd, a2, ba.z), 0.f) * wa.z + fmaxf(fmaf(dd, a3, ba.w), 0.f) * wa.w
            + fmaxf(fmaf(dd, a4, bb.x), 0.f) * wb.x + fmaxf(fmaf(dd, a5, bb.y), 0.f) * wb.y
            + fmaxf(fmaf(dd, a6, bb.z), 0.f) * wb.z + fmaxf(fmaf(dd, a7, bb.w), 0.f) * wb.w;
#pragma unroll
    for (int off = 1; off < 8; off <<= 1) v += __shfl_xor(v, off);
    if ((lane & 31) == 0) zd[i] = v * dd;
}

// ================= agg2 (2 nodes/wave) + fused padded output =================
__global__ __launch_bounds__(256) void k_gather2(const int* __restrict__ srcs,
                                                 const int* __restrict__ row_start,
                                                 const int* __restrict__ row_end,
                                                 const float* __restrict__ dis,
                                                 const float* __restrict__ zd,
                                                 const float* __restrict__ b2,
                                                 float* __restrict__ out, int n) {
    int i = blockIdx.x * 8 + (threadIdx.x >> 5);
    int l = threadIdx.x & 31;
    float acc = 0.f;
    int beg = row_start[i], end = row_end[i];
    for (int j = beg + l; j < end; j += 32)
        acc += zd[srcs[j]];
#pragma unroll
    for (int off = 1; off < 32; off <<= 1) acc += __shfl_xor(acc, off);
    float y = (acc + zd[i]) * dis[i] + b2[0];
    float4 v = make_float4(0.f, 0.f, 0.f, 0.f);
    if (l == 0) v.x = y;
    ((float4*)out)[(size_t)i * 32 + l] = v;
}

extern "C" void kernel_launch(void* const* d_in, const int* in_sizes, int n_in,
                              void* d_out, int out_size, void* d_ws, size_t ws_size,
                              hipStream_t stream) {
    const float* x  = (const float*)d_in[0];
    const int*   ei = (const int*)d_in[1];   // [2, E] int32
    const float* W1 = (const float*)d_in[2];
    const float* b1 = (const float*)d_in[3];
    const float* W2 = (const float*)d_in[4];
    const float* b2 = (const float*)d_in[5];
    float* out = (float*)d_out;

    const int n = N_NODES;
    const int E = N_EDGES;
    const int* src = ei;
    const int* dst = ei + E;

    // ws: pairs_blk int[NBLK*NB*SLOT] (19.6MB) | cnt_blk int[NB*NBLK] (1.2MB) |
    //     srcs_sorted int[NB*BKT_CAP] (8MB) | row_start[n] | row_end[n] |
    //     ovf_cnt[4] | ovf int2[OVF_CAP] | dis f[n] | h1s ushort[n*64] (12.8MB) |
    //     w1t ushort[8192] | zd f[n]            total ~43.5 MB
    int* pairs_blk   = (int*)d_ws;
    int* cnt_blk     = pairs_blk + (size_t)NBLK * NB * SLOT;
    int* srcs_sorted = cnt_blk + (size_t)NB * NBLK;
    int* row_start   = srcs_sorted + (size_t)NB * BKT_CAP;
    int* row_end     = row_start + n;
    int* ovf_cnt     = row_end + n;
    int2* ovf        = (int2*)(ovf_cnt + 4);
    float* dis       = (float*)(ovf + OVF_CAP);
    unsigned short* h1s = (unsigned short*)(dis + n);
    unsigned short* w1t = h1s + (size_t)n * D_HID;
    float* zd        = (float*)(w1t + D_IN * D_HID);

    k_prep<<<32, 256, 0, stream>>>(W1, w1t, ovf_cnt);
    k_escatter<<<NBLK, 256, 0, stream>>>(src, dst, pairs_blk, cnt_blk, ovf_cnt, ovf, E);
    k_bsort<<<NB, 256, 0, stream>>>(pairs_blk, cnt_blk, ovf_cnt, ovf,
                                    srcs_sorted, row_start, row_end, dis, n);

    k_gemm1<<<(n + 63) / 64, 256, 0, stream>>>(x, (const uint4*)w1t, dis, h1s, n);

    k_gather1<<<(n + 7) / 8, 256, 0, stream>>>(srcs_sorted, row_start, row_end, dis,
                                               (const uint4*)h1s, b1, W2, zd, n);
    k_gather2<<<(n + 7) / 8, 256, 0, stream>>>(srcs_sorted, row_start, row_end, dis,
                                               zd, b2, out, n);
}

// Round 11
// 213.220 us; speedup vs baseline: 1.5397x; 1.0616x over previous
//
#include <hip/hip_runtime.h>

#define N_NODES 100000
#define N_EDGES 1600000
#define D_IN 128
#define D_HID 64

#define BKT_SHIFT 8
#define BKT_NODES 256
#define NB 391          // ceil(N_NODES / 256) buckets
#define NBLK 392        // scatter blocks
#define SLOT 32         // slots per (bucket,block): Poisson(10.4), +6.7 sigma
#define SEG4 (SLOT / 4) // uint4s per segment
#define REG4 (NBLK * SEG4)   // uint4s per bucket region = 3136
#define BKT_CAP 5120    // per-bucket capacity in srcs_sorted (mean 4092)
#define OVF_CAP 8192

typedef __attribute__((ext_vector_type(8))) short bf16x8;
typedef __attribute__((ext_vector_type(4))) float f32x4;

__device__ __forceinline__ unsigned short f2b(float f) {
    union { float f; unsigned u; } c; c.f = f;
    unsigned r = (c.u + 0x7FFFu + ((c.u >> 16) & 1u)) >> 16;   // RNE
    return (unsigned short)r;
}
__device__ __forceinline__ float blo(unsigned u) { return __uint_as_float(u << 16); }
__device__ __forceinline__ float bhi(unsigned u) { return __uint_as_float(u & 0xffff0000u); }

// ================= prep: W1 -> bf16 transposed + zero overflow counter =============
__global__ __launch_bounds__(256) void k_prep(const float* __restrict__ W1,
                                              unsigned short* __restrict__ w1t,
                                              int* __restrict__ ovf_cnt) {
    int t = blockIdx.x * 256 + threadIdx.x;          // 8192 threads
    if (t == 0) ovf_cnt[0] = 0;
    int k = t >> 6, f = t & 63;                      // W1 is [128][64]
    w1t[f * D_IN + k] = f2b(W1[t]);
}

// ================= one-pass partition, bucket-major fixed-slot regions ==============
// code = (src << 8) | (dst & 255); region pairs[bucket][block][SLOT]
__global__ __launch_bounds__(256) void k_escatter(const int* __restrict__ src,
                                                  const int* __restrict__ dst,
                                                  int* __restrict__ pairs,
                                                  int* __restrict__ cnt_blk,
                                                  int* __restrict__ ovf_cnt,
                                                  int2* __restrict__ ovf, int E) {
    __shared__ int lcur[NB];
    int tid = threadIdx.x;
    for (int t = tid; t < NB; t += 256) lcur[t] = 0;
    __syncthreads();
    int chunk = (E + NBLK - 1) / NBLK;
    int beg = blockIdx.x * chunk;
    int end = min(beg + chunk, E);
    for (int e = beg + tid; e < end; e += 256) {
        int d = dst[e], s = src[e];
        int bk = d >> BKT_SHIFT;
        int slot = atomicAdd(&lcur[bk], 1);
        if (slot < SLOT)
            pairs[(bk * NBLK + blockIdx.x) * SLOT + slot] = (s << BKT_SHIFT) | (d & (BKT_NODES - 1));
        else {
            int o = atomicAdd(ovf_cnt, 1);
            if (o < OVF_CAP) ovf[o] = make_int2(s, d);
        }
    }
    __syncthreads();
    for (int t = tid; t < NB; t += 256)
        cnt_blk[t * NBLK + blockIdx.x] = min(lcur[t], SLOT);
}

// ================= per-bucket sort: vectorized 2-pass over contiguous region ========
__global__ __launch_bounds__(256) void k_bsort(const uint4* __restrict__ pairs4,
                                               const int* __restrict__ cnt_blk,
                                               const int* __restrict__ ovf_cnt,
                                               const int2* __restrict__ ovf,
                                               int* __restrict__ srcs_sorted,
                                               int* __restrict__ row_start,
                                               int* __restrict__ row_end,
                                               float* __restrict__ dis, int n) {
    __shared__ int segc[NBLK];
    __shared__ int cnt[BKT_NODES];
    __shared__ int exc[BKT_NODES];
    __shared__ int sorted[BKT_CAP];
    __shared__ int nE_sh;
    int b = blockIdx.x;
    int tid = threadIdx.x;
    int node0 = b << BKT_SHIFT;
    int ocnt = min(ovf_cnt[0], OVF_CAP);
    const uint4* region = pairs4 + (size_t)b * REG4;

    for (int i = tid; i < NBLK; i += 256) segc[i] = cnt_blk[b * NBLK + i];
    cnt[tid] = 0;
    __syncthreads();

    // pass 1: histogram (coalesced uint4 reads; a uint4 never crosses a segment)
    for (int i4 = tid; i4 < REG4; i4 += 256) {
        uint4 v = region[i4];
        int c = segc[i4 >> 3];
        int k = (i4 & 7) * 4;
        if (k < c)     atomicAdd(&cnt[v.x & (BKT_NODES - 1)], 1);
        if (k + 1 < c) atomicAdd(&cnt[v.y & (BKT_NODES - 1)], 1);
        if (k + 2 < c) atomicAdd(&cnt[v.z & (BKT_NODES - 1)], 1);
        if (k + 3 < c) atomicAdd(&cnt[v.w & (BKT_NODES - 1)], 1);
    }
    for (int k = tid; k < ocnt; k += 256) {
        int2 e = ovf[k];
        if ((e.y >> BKT_SHIFT) == b) atomicAdd(&cnt[e.y & (BKT_NODES - 1)], 1);
    }
    __syncthreads();

    if (tid < 64) {   // wave-0 exclusive scan of cnt[256]
        int run = 0;
        for (int c = 0; c < BKT_NODES; c += 64) {
            int v = cnt[c + tid];
            int inc = v;
            for (int off = 1; off < 64; off <<= 1) {
                int t2 = __shfl_up(inc, off);
                if (tid >= off) inc += t2;
            }
            exc[c + tid] = run + inc - v;
            run += __shfl(inc, 63);
        }
        if (tid == 63) nE_sh = run;
    }
    __syncthreads();

    int node = node0 + tid;
    if (node < n) {
        int rs = b * BKT_CAP + exc[tid];
        row_start[node] = rs;
        row_end[node] = rs + cnt[tid];
        dis[node] = rsqrtf((float)cnt[tid] + 1.0f);
    }
    int nE = nE_sh;
    __syncthreads();
    cnt[tid] = exc[tid];          // repurpose as per-node cursor
    __syncthreads();

    // pass 2: place into LDS staging (region is L2-hot now)
    for (int i4 = tid; i4 < REG4; i4 += 256) {
        uint4 v = region[i4];
        int c = segc[i4 >> 3];
        int k = (i4 & 7) * 4;
        if (k < c)     { int p = atomicAdd(&cnt[v.x & (BKT_NODES - 1)], 1); sorted[p] = v.x >> BKT_SHIFT; }
        if (k + 1 < c) { int p = atomicAdd(&cnt[v.y & (BKT_NODES - 1)], 1); sorted[p] = v.y >> BKT_SHIFT; }
        if (k + 2 < c) { int p = atomicAdd(&cnt[v.z & (BKT_NODES - 1)], 1); sorted[p] = v.z >> BKT_SHIFT; }
        if (k + 3 < c) { int p = atomicAdd(&cnt[v.w & (BKT_NODES - 1)], 1); sorted[p] = v.w >> BKT_SHIFT; }
    }
    for (int k = tid; k < ocnt; k += 256) {
        int2 e = ovf[k];
        if ((e.y >> BKT_SHIFT) == b) {
            int p = atomicAdd(&cnt[e.y & (BKT_NODES - 1)], 1);
            sorted[p] = e.x;
        }
    }
    __syncthreads();

    // coalesced write-out
    int gbase = b * BKT_CAP;
    for (int k = tid; k < nE; k += 256)
        srcs_sorted[gbase + k] = sorted[k];
}

// ================= layer 1 GEMM via bf16 MFMA, epilogue pre-scales by dis ===========
#define LS 136
__global__ __launch_bounds__(256) void k_gemm1(const float* __restrict__ x,
                                               const uint4* __restrict__ w1t4,
                                               const float* __restrict__ dis,
                                               unsigned short* __restrict__ h1s, int n) {
    __shared__ unsigned short xs[64 * LS];
    __shared__ unsigned short ws[64 * LS];
    int tid = threadIdx.x;
    int node0 = blockIdx.x * 64;

#pragma unroll
    for (int it = 0; it < 4; ++it) {
        int e = tid + it * 256;
        int f = e >> 4, c = e & 15;
        *(uint4*)&ws[f * LS + c * 8] = w1t4[e];
    }
#pragma unroll
    for (int it = 0; it < 8; ++it) {
        int e4 = tid + it * 256;
        int node = e4 >> 5;
        int k = (e4 & 31) * 4;
        float4 v = make_float4(0.f, 0.f, 0.f, 0.f);
        if (node0 + node < n)
            v = ((const float4*)x)[((size_t)(node0 + node) * D_IN + k) >> 2];
        uint2 u;
        u.x = (unsigned)f2b(v.x) | ((unsigned)f2b(v.y) << 16);
        u.y = (unsigned)f2b(v.z) | ((unsigned)f2b(v.w) << 16);
        *(uint2*)&xs[node * LS + k] = u;
    }
    __syncthreads();

    int wv = tid >> 6;
    int lane = tid & 63;
    int m16 = lane & 15;
    int q = lane >> 4;

    bf16x8 afrag[4];
#pragma unroll
    for (int ks = 0; ks < 4; ++ks)
        afrag[ks] = *(const bf16x8*)&xs[(wv * 16 + m16) * LS + ks * 32 + q * 8];

    f32x4 acc[4];
#pragma unroll
    for (int ft = 0; ft < 4; ++ft) acc[ft] = (f32x4){0.f, 0.f, 0.f, 0.f};

#pragma unroll
    for (int ft = 0; ft < 4; ++ft)
#pragma unroll
        for (int ks = 0; ks < 4; ++ks) {
            bf16x8 bfrag = *(const bf16x8*)&ws[(ft * 16 + m16) * LS + ks * 32 + q * 8];
            acc[ft] = __builtin_amdgcn_mfma_f32_16x16x32_bf16(afrag[ks], bfrag, acc[ft], 0, 0, 0);
        }

#pragma unroll
    for (int r = 0; r < 4; ++r) {
        int node = node0 + wv * 16 + q * 4 + r;
        if (node < n) {
            float d = dis[node];
#pragma unroll
            for (int ft = 0; ft < 4; ++ft)
                h1s[(size_t)node * D_HID + ft * 16 + m16] = f2b(acc[ft][r] * d);
        }
    }
}

// ================= fused agg1 + bias + ReLU + dot(W2) -> zd = z*dis =================
__global__ __launch_bounds__(256) void k_gather1(const int* __restrict__ srcs,
                                                 const int* __restrict__ row_start,
                                                 const int* __restrict__ row_end,
                                                 const float* __restrict__ dis,
                                                 const uint4* __restrict__ h4,
                                                 const float* __restrict__ b1,
                                                 const float* __restrict__ W2,
                                                 float* __restrict__ zd, int n) {
    int i = blockIdx.x * 8 + (threadIdx.x >> 5);     // node for this half-wave
    int lane = threadIdx.x & 63;
    int g = (lane >> 3) & 3;  // edge group within half-wave
    int m8 = lane & 7;        // feature block (feats 8*m8 .. 8*m8+7)
    float dd = dis[i];

    float a0, a1, a2, a3, a4, a5, a6, a7;
    {   // self-loop handled by group 0
        uint4 u = h4[(unsigned)i * 8u + m8];
        float w = (g == 0) ? 1.f : 0.f;
        a0 = w * blo(u.x); a1 = w * bhi(u.x);
        a2 = w * blo(u.y); a3 = w * bhi(u.y);
        a4 = w * blo(u.z); a5 = w * bhi(u.z);
        a6 = w * blo(u.w); a7 = w * bhi(u.w);
    }

#define ACC(u) { a0 += blo(u.x); a1 += bhi(u.x); a2 += blo(u.y); a3 += bhi(u.y); \
                 a4 += blo(u.z); a5 += bhi(u.z); a6 += blo(u.w); a7 += bhi(u.w); }
    int end = row_end[i];
    int j = row_start[i] + g;
    for (; j + 4 < end; j += 8) {               // unroll x2: two loads in flight
        int s0 = srcs[j];
        int s1 = srcs[j + 4];
        uint4 u0 = h4[(unsigned)s0 * 8u + m8];
        uint4 u1 = h4[(unsigned)s1 * 8u + m8];
        ACC(u0); ACC(u1);
    }
    if (j < end) {
        int s0 = srcs[j];
        uint4 u0 = h4[(unsigned)s0 * 8u + m8];
        ACC(u0);
    }
#undef ACC

#pragma unroll
    for (int off = 8; off < 32; off <<= 1) {
        a0 += __shfl_xor(a0, off); a1 += __shfl_xor(a1, off);
        a2 += __shfl_xor(a2, off); a3 += __shfl_xor(a3, off);
        a4 += __shfl_xor(a4, off); a5 += __shfl_xor(a5, off);
        a6 += __shfl_xor(a6, off); a7 += __shfl_xor(a7, off);
    }
    float4 ba = ((const float4*)b1)[m8 * 2];
    float4 bb = ((const float4*)b1)[m8 * 2 + 1];
    float4 wa = ((const float4*)W2)[m8 * 2];
    float4 wb = ((const float4*)W2)[m8 * 2 + 1];
    float v = fmaxf(fmaf(dd, a0, ba.x), 0.f) * wa.x + fmaxf(fmaf(dd, a1, ba.y), 0.f) * wa.y
            + fmaxf(fmaf(dd, a2, ba.z), 0.f) * wa.z + fmaxf(fmaf(dd, a3, ba.w), 0.f) * wa.w
            + fmaxf(fmaf(dd, a4, bb.x), 0.f) * wb.x + fmaxf(fmaf(dd, a5, bb.y), 0.f) * wb.y
            + fmaxf(fmaf(dd, a6, bb.z), 0.f) * wb.z + fmaxf(fmaf(dd, a7, bb.w), 0.f) * wb.w;
#pragma unroll
    for (int off = 1; off < 8; off <<= 1) v += __shfl_xor(v, off);
    if ((lane & 31) == 0) zd[i] = v * dd;
}

// ================= agg2 (2 nodes/wave) + fused padded output =================
__global__ __launch_bounds__(256) void k_gather2(const int* __restrict__ srcs,
                                                 const int* __restrict__ row_start,
                                                 const int* __restrict__ row_end,
                                                 const float* __restrict__ dis,
                                                 const float* __restrict__ zd,
                                                 const float* __restrict__ b2,
                                                 float* __restrict__ out, int n) {
    int i = blockIdx.x * 8 + (threadIdx.x >> 5);
    int l = threadIdx.x & 31;
    float acc = 0.f;
    int beg = row_start[i], end = row_end[i];
    for (int j = beg + l; j < end; j += 32)
        acc += zd[srcs[j]];
#pragma unroll
    for (int off = 1; off < 32; off <<= 1) acc += __shfl_xor(acc, off);
    float y = (acc + zd[i]) * dis[i] + b2[0];
    float4 v = make_float4(0.f, 0.f, 0.f, 0.f);
    if (l == 0) v.x = y;
    ((float4*)out)[(size_t)i * 32 + l] = v;
}

extern "C" void kernel_launch(void* const* d_in, const int* in_sizes, int n_in,
                              void* d_out, int out_size, void* d_ws, size_t ws_size,
                              hipStream_t stream) {
    const float* x  = (const float*)d_in[0];
    const int*   ei = (const int*)d_in[1];   // [2, E] int32
    const float* W1 = (const float*)d_in[2];
    const float* b1 = (const float*)d_in[3];
    const float* W2 = (const float*)d_in[4];
    const float* b2 = (const float*)d_in[5];
    float* out = (float*)d_out;

    const int n = N_NODES;
    const int E = N_EDGES;
    const int* src = ei;
    const int* dst = ei + E;

    // ws: pairs int[NB*NBLK*SLOT] (19.6MB) | cnt_blk int[NB*NBLK] (613KB) |
    //     srcs_sorted int[NB*BKT_CAP] (8MB) | row_start[n] | row_end[n] |
    //     ovf_cnt[4] | ovf int2[OVF_CAP] | dis f[n] | h1s ushort[n*64] (12.8MB) |
    //     w1t ushort[8192] | zd f[n]
    int* pairs       = (int*)d_ws;
    int* cnt_blk     = pairs + (size_t)NB * NBLK * SLOT;
    int* srcs_sorted = cnt_blk + (size_t)NB * NBLK;
    int* row_start   = srcs_sorted + (size_t)NB * BKT_CAP;
    int* row_end     = row_start + n;
    int* ovf_cnt     = row_end + n;
    int2* ovf        = (int2*)(ovf_cnt + 4);
    float* dis       = (float*)(ovf + OVF_CAP);
    unsigned short* h1s = (unsigned short*)(dis + n);
    unsigned short* w1t = h1s + (size_t)n * D_HID;
    float* zd        = (float*)(w1t + D_IN * D_HID);

    k_prep<<<32, 256, 0, stream>>>(W1, w1t, ovf_cnt);
    k_escatter<<<NBLK, 256, 0, stream>>>(src, dst, pairs, cnt_blk, ovf_cnt, ovf, E);
    k_bsort<<<NB, 256, 0, stream>>>((const uint4*)pairs, cnt_blk, ovf_cnt, ovf,
                                    srcs_sorted, row_start, row_end, dis, n);

    k_gemm1<<<(n + 63) / 64, 256, 0, stream>>>(x, (const uint4*)w1t, dis, h1s, n);

    k_gather1<<<(n + 7) / 8, 256, 0, stream>>>(srcs_sorted, row_start, row_end, dis,
                                               (const uint4*)h1s, b1, W2, zd, n);
    k_gather2<<<(n + 7) / 8, 256, 0, stream>>>(srcs_sorted, row_start, row_end, dis,
                                               zd, b2, out, n);
}